// Round 1
// baseline (947.720 us; speedup 1.0000x reference)
//
#include <hip/hip_runtime.h>
#include <hip/hip_bf16.h>
#include <cstdint>
#include <cstddef>

typedef __bf16 bf16;
typedef __bf16 bf16x8 __attribute__((ext_vector_type(8)));
typedef __bf16 bf16x4 __attribute__((ext_vector_type(4)));
typedef float  f32x4  __attribute__((ext_vector_type(4)));

typedef __attribute__((address_space(1))) void gvoid_t;
typedef __attribute__((address_space(3))) void lvoid_t;

// async global->LDS, 16B per lane; LDS dest must be wave-uniform base (HW adds lane*16)
#define GLD_LDS16(g, l) __builtin_amdgcn_global_load_lds( \
    (gvoid_t*)(uintptr_t)(g), (lvoid_t*)(uint32_t)(uintptr_t)(l), 16, 0, 0)

// ---------------------------------------------------------------------------
// Weight transpose + f32->bf16 cast:  in [R][C] f32  ->  out [C][R] bf16
// ---------------------------------------------------------------------------
__global__ __launch_bounds__(256) void transpose_cast(
    const float* __restrict__ in, bf16* __restrict__ out, int R, int C)
{
  __shared__ float tile[32][33];
  const int bx = blockIdx.x;   // C/32
  const int by = blockIdx.y;   // R/32
  const int tx = threadIdx.x;  // 0..31
  const int ty = threadIdx.y;  // 0..7
#pragma unroll
  for (int i = 0; i < 32; i += 8)
    tile[ty + i][tx] = in[(size_t)(by * 32 + ty + i) * C + bx * 32 + tx];
  __syncthreads();
#pragma unroll
  for (int i = 0; i < 32; i += 8)
    out[(size_t)(bx * 32 + ty + i) * R + by * 32 + tx] = (bf16)tile[tx][ty + i];
}

// ---------------------------------------------------------------------------
// LayerNorm over H=1024, f32 in -> bf16 out. One block (256 thr) per row.
// ---------------------------------------------------------------------------
__global__ __launch_bounds__(256) void ln_row(
    const float* __restrict__ x, const float* __restrict__ w,
    const float* __restrict__ b, bf16* __restrict__ out)
{
  const int row = blockIdx.x;
  const int tid = threadIdx.x;
  const float4 v = ((const float4*)(x + (size_t)row * 1024))[tid];
  float s  = v.x + v.y + v.z + v.w;
  float ss = v.x * v.x + v.y * v.y + v.z * v.z + v.w * v.w;
#pragma unroll
  for (int off = 32; off > 0; off >>= 1) {
    s  += __shfl_down(s, off);
    ss += __shfl_down(ss, off);
  }
  __shared__ float red[8];
  const int wid = tid >> 6, lane = tid & 63;
  if (lane == 0) { red[wid] = s; red[4 + wid] = ss; }
  __syncthreads();
  s  = red[0] + red[1] + red[2] + red[3];
  ss = red[4] + red[5] + red[6] + red[7];
  const float mu   = s * (1.f / 1024.f);
  const float var  = ss * (1.f / 1024.f) - mu * mu;
  const float rstd = rsqrtf(var + 1e-5f);
  const float4 wv = ((const float4*)w)[tid];
  const float4 bv = ((const float4*)b)[tid];
  bf16x4 ov;
  ov[0] = (bf16)((v.x - mu) * rstd * wv.x + bv.x);
  ov[1] = (bf16)((v.y - mu) * rstd * wv.y + bv.y);
  ov[2] = (bf16)((v.z - mu) * rstd * wv.z + bv.z);
  ov[3] = (bf16)((v.w - mu) * rstd * wv.w + bv.w);
  *(bf16x4*)(out + (size_t)row * 1024 + tid * 4) = ov;
}

// ---------------------------------------------------------------------------
// GEMM: C[M,N] = A[M,K] (bf16) * BT[N,K]^T (bf16) + bias, epilogue variants.
// 128x128 tile, BK=32, 4 waves (2x2), 4x4 mfma_f32_16x16x32_bf16 frags/wave.
// EPI: 0 = bias -> bf16          (v proj)
//      1 = bias -> elu+1 -> bf16 (q,k feature map)
//      2 = bias + resid -> f32   (o proj / final proj)
//      3 = bias -> gelu -> bf16  (fc)
// ---------------------------------------------------------------------------
template <int EPI>
__global__ __launch_bounds__(256) void gemm_bt(
    const bf16* __restrict__ A, const bf16* __restrict__ BT,
    const float* __restrict__ bias, const float* __restrict__ resid,
    void* __restrict__ outp, int M, int N, int K)
{
  __shared__ __align__(16) bf16 sA[128 * 32];
  __shared__ __align__(16) bf16 sB[128 * 32];
  const int tid  = threadIdx.x;
  const int wid  = tid >> 6;
  const int lane = tid & 63;
  const int row0 = blockIdx.y << 7;
  const int col0 = blockIdx.x << 7;
  const int wr = wid >> 1, wc = wid & 1;
  const int srow = tid >> 2;           // 0..63
  const int scol = (tid & 3) << 3;     // 0,8,16,24

  f32x4 acc[4][4] = {};

  const bf16* Ab = A  + (size_t)(row0 + srow) * K + scol;
  const bf16* Bb = BT + (size_t)(col0 + srow) * K + scol;
  const size_t rstep = (size_t)K << 6; // 64 rows

  char* sAb = (char*)sA + wid * 1024;
  char* sBb = (char*)sB + wid * 1024;

  const int lk   = (lane >> 4) << 3;   // k-offset of fragment
  const int lr16 = lane & 15;
  const int lr4  = (lane >> 4) << 2;

  for (int k0 = 0; k0 < K; k0 += 32) {
    __syncthreads();
    GLD_LDS16(Ab + k0,         sAb);
    GLD_LDS16(Ab + rstep + k0, sAb + 4096);
    GLD_LDS16(Bb + k0,         sBb);
    GLD_LDS16(Bb + rstep + k0, sBb + 4096);
    __syncthreads();
    bf16x8 af[4], bfr[4];
#pragma unroll
    for (int m = 0; m < 4; ++m)
      af[m] = *(const bf16x8*)&sA[(wr * 64 + m * 16 + lr16) * 32 + lk];
#pragma unroll
    for (int n = 0; n < 4; ++n)
      bfr[n] = *(const bf16x8*)&sB[(wc * 64 + n * 16 + lr16) * 32 + lk];
#pragma unroll
    for (int m = 0; m < 4; ++m)
#pragma unroll
      for (int n = 0; n < 4; ++n)
        acc[m][n] = __builtin_amdgcn_mfma_f32_16x16x32_bf16(af[m], bfr[n], acc[m][n], 0, 0, 0);
  }

#pragma unroll
  for (int m = 0; m < 4; ++m) {
#pragma unroll
    for (int n = 0; n < 4; ++n) {
      const int c_i = col0 + wc * 64 + n * 16 + lr16;
      const float bv = bias[c_i];
#pragma unroll
      for (int j = 0; j < 4; ++j) {
        const int r_i = row0 + wr * 64 + m * 16 + lr4 + j;
        const size_t idx = (size_t)r_i * N + c_i;
        float val = acc[m][n][j] + bv;
        if constexpr (EPI == 0) {
          ((bf16*)outp)[idx] = (bf16)val;
        } else if constexpr (EPI == 1) {
          ((bf16*)outp)[idx] = (bf16)(val > 0.f ? val + 1.f : __expf(val));
        } else if constexpr (EPI == 2) {
          ((float*)outp)[idx] = val + resid[idx];
        } else {
          const float u  = 0.7978845608028654f * (val + 0.044715f * val * val * val);
          const float th = 1.f - 2.f / (__expf(2.f * u) + 1.f);
          ((bf16*)outp)[idx] = (bf16)(0.5f * val * (1.f + th));
        }
      }
    }
  }
}

// ---------------------------------------------------------------------------
// kv partials: per (b,h) and 512-token chunk, kv[d][e] = sum_t kf[t,d]*v[t,e],
// ksum[d] = sum_t kf[t,d].  grid = 64 heads * 8 chunks.
// ---------------------------------------------------------------------------
__global__ __launch_bounds__(256) void kv_part_kernel(
    const bf16* __restrict__ kf, const bf16* __restrict__ v,
    float* __restrict__ kv_part, float* __restrict__ ksum_part)
{
  const int bh = blockIdx.x >> 3, ch = blockIdx.x & 7;
  const int b = bh >> 4, h = bh & 15;
  const int tid = threadIdx.x;
  const int e = tid & 63, dg = tid >> 6;        // thread owns d in [dg*16, dg*16+16)
  const size_t grow0 = (size_t)b * 4096 + (size_t)ch * 512;
  const size_t cbase = (size_t)h * 64;
  __shared__ bf16 skf[8][64], sv[8][64];
  float accum[16];
#pragma unroll
  for (int i = 0; i < 16; ++i) accum[i] = 0.f;
  float ks = 0.f;
  const int tt = tid >> 5, cc = (tid & 31) << 1;
  for (int t0 = 0; t0 < 512; t0 += 8) {
    __syncthreads();
    const size_t base = (grow0 + t0 + tt) * 1024 + cbase + cc;
    *(uint32_t*)&skf[tt][cc] = *(const uint32_t*)(kf + base);
    *(uint32_t*)&sv[tt][cc]  = *(const uint32_t*)(v + base);
    __syncthreads();
#pragma unroll
    for (int q = 0; q < 8; ++q) {
      const float vv = (float)sv[q][e];
#pragma unroll
      for (int dd = 0; dd < 16; ++dd)
        accum[dd] += (float)skf[q][dg * 16 + dd] * vv;
    }
    if (tid < 64) {
#pragma unroll
      for (int q = 0; q < 8; ++q) ks += (float)skf[q][tid];
    }
  }
  float* op = kv_part + (size_t)blockIdx.x * 4096 + (size_t)(dg * 16) * 64 + e;
#pragma unroll
  for (int dd = 0; dd < 16; ++dd) op[dd * 64] = accum[dd];
  if (tid < 64) ksum_part[(size_t)blockIdx.x * 64 + tid] = ks;
}

__global__ __launch_bounds__(256) void kv_reduce(
    const float* __restrict__ kvp, const float* __restrict__ ksp,
    float* __restrict__ kvf, float* __restrict__ ksf)
{
  const int bh = blockIdx.x;
  const int tid = threadIdx.x;
  for (int i = tid; i < 4096; i += 256) {
    float s = 0.f;
#pragma unroll
    for (int ch = 0; ch < 8; ++ch) s += kvp[((size_t)bh * 8 + ch) * 4096 + i];
    kvf[(size_t)bh * 4096 + i] = s;
  }
  if (tid < 64) {
    float s = 0.f;
#pragma unroll
    for (int ch = 0; ch < 8; ++ch) s += ksp[((size_t)bh * 8 + ch) * 64 + tid];
    ksf[(size_t)bh * 64 + tid] = s;
  }
}

// ---------------------------------------------------------------------------
// attn out: out[t,e] = (qf[t,:].kv[:,e]) / (qf[t,:].ksum + 1e-6) -> bf16
// grid = 64 heads * 64 row-blocks of 64 rows. kv column held in registers.
// ---------------------------------------------------------------------------
__global__ __launch_bounds__(256) void attn_out_kernel(
    const bf16* __restrict__ qf, const float* __restrict__ kvf,
    const float* __restrict__ ksf, bf16* __restrict__ attn)
{
  const int bh = blockIdx.x >> 6, rb = blockIdx.x & 63;
  const int b = bh >> 4, h = bh & 15;
  const int tid = threadIdx.x;
  const int e = tid & 63, rbase = (tid >> 6) << 4;
  __shared__ __align__(16) bf16 sqf[64][64];
  __shared__ float sks[64];
  const size_t grow0 = (size_t)b * 4096 + (size_t)rb * 64;

  {
    const int rr = tid >> 2, c0 = (tid & 3) << 4;
    const bf16* src = qf + (grow0 + rr) * 1024 + h * 64 + c0;
    *(bf16x8*)&sqf[rr][c0]     = *(const bf16x8*)src;
    *(bf16x8*)&sqf[rr][c0 + 8] = *(const bf16x8*)(src + 8);
  }
  if (tid < 64) sks[tid] = ksf[(size_t)bh * 64 + tid];

  float kcol[64];
#pragma unroll
  for (int d = 0; d < 64; ++d) kcol[d] = kvf[(size_t)bh * 4096 + d * 64 + e];

  __syncthreads();

  for (int rr = 0; rr < 16; ++rr) {
    const int r = rbase + rr;
    bf16x8 q8[8];
#pragma unroll
    for (int i = 0; i < 8; ++i) q8[i] = *(const bf16x8*)&sqf[r][i * 8];
    float sk = 0.f, sv = 0.f;
#pragma unroll
    for (int i = 0; i < 8; ++i)
#pragma unroll
      for (int jj = 0; jj < 8; ++jj) {
        const float qd = (float)q8[i][jj];
        sk += qd * sks[i * 8 + jj];
        sv += qd * kcol[i * 8 + jj];
      }
    attn[(grow0 + r) * 1024 + h * 64 + e] = (bf16)(sv / (sk + 1e-6f));
  }
}

// ---------------------------------------------------------------------------
// launch
// ---------------------------------------------------------------------------
extern "C" void kernel_launch(void* const* d_in, const int* in_sizes, int n_in,
                              void* d_out, int out_size, void* d_ws, size_t ws_size,
                              hipStream_t stream)
{
  const float* x    = (const float*)d_in[0];
  const float* ln1w = (const float*)d_in[1];
  const float* ln1b = (const float*)d_in[2];
  const float* qw   = (const float*)d_in[3];
  const float* qb   = (const float*)d_in[4];
  const float* kw   = (const float*)d_in[5];
  const float* kb   = (const float*)d_in[6];
  const float* vw   = (const float*)d_in[7];
  const float* vb   = (const float*)d_in[8];
  const float* ow   = (const float*)d_in[9];
  const float* ob   = (const float*)d_in[10];
  const float* ln2w = (const float*)d_in[11];
  const float* ln2b = (const float*)d_in[12];
  const float* fcw  = (const float*)d_in[13];
  const float* fcb  = (const float*)d_in[14];
  const float* pjw  = (const float*)d_in[15];
  const float* pjb  = (const float*)d_in[16];
  float* out = (float*)d_out;
  char* ws = (char*)d_ws;

  // workspace layout (bytes). region0 [0,134217728) holds lnx/qf/kf/v in
  // phase 1 and is reused for h_mlp in the MLP phase.
  constexpr size_t O_LNX  = 0;
  constexpr size_t O_QF   = 33554432;
  constexpr size_t O_KF   = 67108864;
  constexpr size_t O_V    = 100663296;
  constexpr size_t O_HMLP = 0;
  constexpr size_t O_KVP  = 134217728;
  constexpr size_t O_KSP  = 142606336;
  constexpr size_t O_KVF  = 142737408;
  constexpr size_t O_KSF  = 143785984;
  constexpr size_t O_ATTN = 143802368;
  constexpr size_t O_LN2  = 177356800;
  constexpr size_t O_WQ   = 210911232;
  constexpr size_t O_WK   = 213008384;
  constexpr size_t O_WV   = 215105536;
  constexpr size_t O_WO   = 217202688;
  constexpr size_t O_WFC  = 219299840;
  constexpr size_t O_WPJ  = 227688448;

  bf16* lnx  = (bf16*)(ws + O_LNX);
  bf16* qfb  = (bf16*)(ws + O_QF);
  bf16* kfb  = (bf16*)(ws + O_KF);
  bf16* vbuf = (bf16*)(ws + O_V);
  bf16* hmlp = (bf16*)(ws + O_HMLP);
  float* kvp = (float*)(ws + O_KVP);
  float* ksp = (float*)(ws + O_KSP);
  float* kvf = (float*)(ws + O_KVF);
  float* ksf = (float*)(ws + O_KSF);
  bf16* attn = (bf16*)(ws + O_ATTN);
  bf16* ln2h = (bf16*)(ws + O_LN2);
  bf16* wqT  = (bf16*)(ws + O_WQ);
  bf16* wkT  = (bf16*)(ws + O_WK);
  bf16* wvT  = (bf16*)(ws + O_WV);
  bf16* woT  = (bf16*)(ws + O_WO);
  bf16* wfcT = (bf16*)(ws + O_WFC);
  bf16* wpjT = (bf16*)(ws + O_WPJ);

  const dim3 tb(32, 8);
  transpose_cast<<<dim3(32, 32),  tb, 0, stream>>>(qw,  wqT, 1024, 1024);
  transpose_cast<<<dim3(32, 32),  tb, 0, stream>>>(kw,  wkT, 1024, 1024);
  transpose_cast<<<dim3(32, 32),  tb, 0, stream>>>(vw,  wvT, 1024, 1024);
  transpose_cast<<<dim3(32, 32),  tb, 0, stream>>>(ow,  woT, 1024, 1024);
  transpose_cast<<<dim3(128, 32), tb, 0, stream>>>(fcw, wfcT, 1024, 4096);
  transpose_cast<<<dim3(32, 128), tb, 0, stream>>>(pjw, wpjT, 4096, 1024);

  ln_row<<<16384, 256, 0, stream>>>(x, ln1w, ln1b, lnx);

  gemm_bt<1><<<dim3(8, 128), 256, 0, stream>>>(lnx, wqT, qb, nullptr, qfb, 16384, 1024, 1024);
  gemm_bt<1><<<dim3(8, 128), 256, 0, stream>>>(lnx, wkT, kb, nullptr, kfb, 16384, 1024, 1024);
  gemm_bt<0><<<dim3(8, 128), 256, 0, stream>>>(lnx, wvT, vb, nullptr, vbuf, 16384, 1024, 1024);

  kv_part_kernel<<<512, 256, 0, stream>>>(kfb, vbuf, kvp, ksp);
  kv_reduce<<<64, 256, 0, stream>>>(kvp, ksp, kvf, ksf);
  attn_out_kernel<<<4096, 256, 0, stream>>>(qfb, kvf, ksf, attn);

  // y1 = x + attn @ o_w + o_b   (written into d_out, f32)
  gemm_bt<2><<<dim3(8, 128), 256, 0, stream>>>(attn, woT, ob, x, out, 16384, 1024, 1024);

  ln_row<<<16384, 256, 0, stream>>>(out, ln2w, ln2b, ln2h);

  gemm_bt<3><<<dim3(32, 128), 256, 0, stream>>>(ln2h, wfcT, fcb, nullptr, hmlp, 16384, 4096, 1024);

  // out = y1 + h_mlp @ proj_w + proj_b  (in-place on d_out: read-before-write per element)
  gemm_bt<2><<<dim3(8, 128), 256, 0, stream>>>(hmlp, wpjT, pjb, out, out, 16384, 1024, 4096);
}

// Round 2
// 734.321 us; speedup vs baseline: 1.2906x; 1.2906x over previous
//
#include <hip/hip_runtime.h>
#include <hip/hip_bf16.h>
#include <cstdint>
#include <cstddef>

typedef __bf16 bf16;
typedef __bf16 bf16x8 __attribute__((ext_vector_type(8)));
typedef __bf16 bf16x4 __attribute__((ext_vector_type(4)));
typedef float  f32x4  __attribute__((ext_vector_type(4)));

typedef __attribute__((address_space(1))) void gvoid_t;
typedef __attribute__((address_space(3))) void lvoid_t;

// async global->LDS, 16B per lane; LDS dest must be wave-uniform base (HW adds lane*16)
#define GLD_LDS16(g, l) __builtin_amdgcn_global_load_lds( \
    (gvoid_t*)(uintptr_t)(g), (lvoid_t*)(uint32_t)(uintptr_t)(l), 16, 0, 0)

#define SBAR() __builtin_amdgcn_s_barrier()
#define SCHED_FENCE() __builtin_amdgcn_sched_barrier(0)
#define WAIT_VM(n) asm volatile("s_waitcnt vmcnt(" #n ")" ::: "memory")
#define WAIT_LGKM0() asm volatile("s_waitcnt lgkmcnt(0)" ::: "memory")

// ---------------------------------------------------------------------------
// Weight transpose + f32->bf16 cast:  in [R][C] f32  ->  out [C][R] bf16
// ---------------------------------------------------------------------------
__global__ __launch_bounds__(256) void transpose_cast(
    const float* __restrict__ in, bf16* __restrict__ out, int R, int C)
{
  __shared__ float tile[32][33];
  const int bx = blockIdx.x;   // C/32
  const int by = blockIdx.y;   // R/32
  const int tx = threadIdx.x;  // 0..31
  const int ty = threadIdx.y;  // 0..7
#pragma unroll
  for (int i = 0; i < 32; i += 8)
    tile[ty + i][tx] = in[(size_t)(by * 32 + ty + i) * C + bx * 32 + tx];
  __syncthreads();
#pragma unroll
  for (int i = 0; i < 32; i += 8)
    out[(size_t)(bx * 32 + ty + i) * R + by * 32 + tx] = (bf16)tile[tx][ty + i];
}

// ---------------------------------------------------------------------------
// LayerNorm over H=1024, f32 in -> bf16 out. One block (256 thr) per row.
// ---------------------------------------------------------------------------
__global__ __launch_bounds__(256) void ln_row(
    const float* __restrict__ x, const float* __restrict__ w,
    const float* __restrict__ b, bf16* __restrict__ out)
{
  const int row = blockIdx.x;
  const int tid = threadIdx.x;
  const float4 v = ((const float4*)(x + (size_t)row * 1024))[tid];
  float s  = v.x + v.y + v.z + v.w;
  float ss = v.x * v.x + v.y * v.y + v.z * v.z + v.w * v.w;
#pragma unroll
  for (int off = 32; off > 0; off >>= 1) {
    s  += __shfl_down(s, off);
    ss += __shfl_down(ss, off);
  }
  __shared__ float red[8];
  const int wid = tid >> 6, lane = tid & 63;
  if (lane == 0) { red[wid] = s; red[4 + wid] = ss; }
  __syncthreads();
  s  = red[0] + red[1] + red[2] + red[3];
  ss = red[4] + red[5] + red[6] + red[7];
  const float mu   = s * (1.f / 1024.f);
  const float var  = ss * (1.f / 1024.f) - mu * mu;
  const float rstd = rsqrtf(var + 1e-5f);
  const float4 wv = ((const float4*)w)[tid];
  const float4 bv = ((const float4*)b)[tid];
  bf16x4 ov;
  ov[0] = (bf16)((v.x - mu) * rstd * wv.x + bv.x);
  ov[1] = (bf16)((v.y - mu) * rstd * wv.y + bv.y);
  ov[2] = (bf16)((v.z - mu) * rstd * wv.z + bv.z);
  ov[3] = (bf16)((v.w - mu) * rstd * wv.w + bv.w);
  *(bf16x4*)(out + (size_t)row * 1024 + tid * 4) = ov;
}

// ---------------------------------------------------------------------------
// 256x256 8-phase GEMM: C[M,N] = A[M,K] (bf16) * BT[N,K]^T (bf16) + bias.
// 512 threads = 8 waves (2M x 4N); per-wave 128x64 output (8x4 16x16 frags).
// LDS 128KB: per matrix 2 dbuf x 2 K-halves of [256 rows][32 cols] bf16.
// Stage: 1 half-tile (16KB, 2 gld/thread) per phase; counted vmcnt(8);
// XOR swizzle slot^=(row>>1)&3 on BOTH the global source and the ds_read.
// EPI: 0 bias->bf16 | 1 bias->elu+1->bf16 | 2 bias+resid->f32 | 3 bias->gelu->bf16
// ---------------------------------------------------------------------------
template <int EPI>
__global__ __launch_bounds__(512, 2) void gemm256(
    const bf16* __restrict__ A, const bf16* __restrict__ BT,
    const float* __restrict__ bias, const float* __restrict__ resid,
    void* __restrict__ outp, int M, int N, int K, int nx)
{
  __shared__ __align__(16) char lds[131072];
  const int tid  = threadIdx.x;
  const int wid  = tid >> 6, lane = tid & 63;
  const int wr   = wid >> 2, wc = wid & 3;
  const int ln15 = lane & 15, lhi = lane >> 4;

  // chunked XCD swizzle + row-major logical tile order
  const int nwg = (int)gridDim.x;
  const int cpx = nwg >> 3;
  const int bid = (int)blockIdx.x;
  const int lg  = (bid & 7) * cpx + (bid >> 3);
  const int bx  = lg % nx, by = lg / nx;
  const int row0 = by << 8, col0 = bx << 8;

  // staging setup: thread covers slot s = li*512 + tid; row = li*128 + tid>>2
  const int srow = tid >> 2;                       // 0..127
  const int swz  = (tid & 3) ^ ((srow >> 1) & 3);  // same for both li (128 = 0 mod 4 after >>1.. &3)
  const bf16* aS = A  + (size_t)(row0 + srow) * K + swz * 8;
  const bf16* bS = BT + (size_t)(col0 + srow) * K + swz * 8;
  const size_t rjump = (size_t)K << 7;             // +128 rows
  char* ldsAw = lds + wid * 1024;                  // A base at 0
  char* ldsBw = lds + 65536 + wid * 1024;          // B base at 64KB

  // read setup (per-thread constant swizzled base byte within a half-buffer)
  const int rA  = (wr << 7) + ln15;                // A row for this lane (frag m adds m*16)
  const int rB  = (wc << 6) + ln15;                // B row (frag n adds n*16)
  const int aRd = rA * 64 + ((lhi ^ ((rA >> 1) & 3)) << 4);
  const int bRd = rB * 64 + ((lhi ^ ((rB >> 1) & 3)) << 4);

  f32x4 acc[8][4] = {};
  bf16x8 af[4], bf[4];
  const int nt = K >> 6;

#define STG_A(D, KH, KT) do { \
    const bf16* g_ = aS + (size_t)(KT) * 64 + (KH) * 32; \
    char* l_ = ldsAw + (D) * 32768 + (KH) * 16384; \
    GLD_LDS16(g_, l_); GLD_LDS16(g_ + rjump, l_ + 8192); } while (0)
#define STG_B(D, KH, KT) do { \
    const bf16* g_ = bS + (size_t)(KT) * 64 + (KH) * 32; \
    char* l_ = ldsBw + (D) * 32768 + (KH) * 16384; \
    GLD_LDS16(g_, l_); GLD_LDS16(g_ + rjump, l_ + 8192); } while (0)
#define LD_A(KS, MH) do { _Pragma("unroll") \
    for (int mi_ = 0; mi_ < 4; ++mi_) \
      af[mi_] = *(const bf16x8*)(aBase + (KS) * 16384 + ((MH) * 4 + mi_) * 1024); } while (0)
#define LD_B(KS) do { _Pragma("unroll") \
    for (int ni_ = 0; ni_ < 4; ++ni_) \
      bf[ni_] = *(const bf16x8*)(bBase + (KS) * 16384 + ni_ * 1024); } while (0)
#define MFMA16(MH) do { \
    __builtin_amdgcn_s_setprio(1); \
    _Pragma("unroll") for (int mi_ = 0; mi_ < 4; ++mi_) \
    _Pragma("unroll") for (int ni_ = 0; ni_ < 4; ++ni_) \
      acc[(MH) * 4 + mi_][ni_] = __builtin_amdgcn_mfma_f32_16x16x32_bf16( \
          af[mi_], bf[ni_], acc[(MH) * 4 + mi_][ni_], 0, 0, 0); \
    __builtin_amdgcn_s_setprio(0); } while (0)

  // prologue: T0 full + T1 h0  (6 half-tiles, 12 loads/thread)
  STG_A(0, 0, 0); STG_B(0, 0, 0);
  STG_A(0, 1, 0); STG_B(0, 1, 0);
  STG_A(1, 0, 1); STG_B(1, 0, 1);
  WAIT_VM(8);            // h0(T0) landed
  SBAR();

  for (int kt = 0; kt < nt; ++kt) {
    const int d  = kt & 1;
    const int dn = d ^ 1;
    const bool s01 = (kt + 1 < nt);
    const bool s23 = (kt + 2 < nt);
    const char* aBase = (const char*)lds + d * 32768 + aRd;
    const char* bBase = (const char*)lds + 65536 + d * 32768 + bRd;

    // phase 0: ks=0, mh=0
    LD_B(0); LD_A(0, 0);
    if (s01) STG_A(dn, 1, kt + 1);
    SBAR(); WAIT_LGKM0(); SCHED_FENCE();
    MFMA16(0);
    SCHED_FENCE(); SBAR();

    // phase 1: ks=0, mh=1  (reuse bf)
    LD_A(0, 1);
    if (s01) STG_B(dn, 1, kt + 1);
    SBAR(); WAIT_LGKM0(); SCHED_FENCE();
    MFMA16(1);
    SCHED_FENCE();
    if (s01) { WAIT_VM(8); } else { WAIT_VM(0); }   // protect h1(T)
    SBAR();

    // phase 2: ks=1, mh=0
    LD_B(1); LD_A(1, 0);
    if (s23) STG_A(d, 0, kt + 2);
    SBAR(); WAIT_LGKM0(); SCHED_FENCE();
    MFMA16(0);
    SCHED_FENCE(); SBAR();

    // phase 3: ks=1, mh=1
    LD_A(1, 1);
    if (s23) STG_B(d, 0, kt + 2);
    SBAR(); WAIT_LGKM0(); SCHED_FENCE();
    MFMA16(1);
    SCHED_FENCE();
    if (s23) { WAIT_VM(8); } else if (s01) { WAIT_VM(4); }  // protect h0(T+1)
    SBAR();
  }

#undef STG_A
#undef STG_B
#undef LD_A
#undef LD_B
#undef MFMA16

  // epilogue
  const int lr4 = lhi << 2;
#pragma unroll
  for (int m = 0; m < 8; ++m) {
#pragma unroll
    for (int n = 0; n < 4; ++n) {
      const int c_i = col0 + wc * 64 + n * 16 + ln15;
      const float bv = bias[c_i];
#pragma unroll
      for (int j = 0; j < 4; ++j) {
        const int r_i = row0 + wr * 128 + m * 16 + lr4 + j;
        const size_t idx = (size_t)r_i * N + c_i;
        float val = acc[m][n][j] + bv;
        if constexpr (EPI == 0) {
          ((bf16*)outp)[idx] = (bf16)val;
        } else if constexpr (EPI == 1) {
          ((bf16*)outp)[idx] = (bf16)(val > 0.f ? val + 1.f : __expf(val));
        } else if constexpr (EPI == 2) {
          ((float*)outp)[idx] = val + resid[idx];
        } else {
          const float u  = 0.7978845608028654f * (val + 0.044715f * val * val * val);
          const float th = 1.f - 2.f / (__expf(2.f * u) + 1.f);
          ((bf16*)outp)[idx] = (bf16)(0.5f * val * (1.f + th));
        }
      }
    }
  }
}

// ---------------------------------------------------------------------------
// kv partials: per (b,h) and 512-token chunk, kv[d][e] = sum_t kf[t,d]*v[t,e],
// ksum[d] = sum_t kf[t,d].  grid = 64 heads * 8 chunks.
// ---------------------------------------------------------------------------
__global__ __launch_bounds__(256) void kv_part_kernel(
    const bf16* __restrict__ kf, const bf16* __restrict__ v,
    float* __restrict__ kv_part, float* __restrict__ ksum_part)
{
  const int bh = blockIdx.x >> 3, ch = blockIdx.x & 7;
  const int b = bh >> 4, h = bh & 15;
  const int tid = threadIdx.x;
  const int e = tid & 63, dg = tid >> 6;
  const size_t grow0 = (size_t)b * 4096 + (size_t)ch * 512;
  const size_t cbase = (size_t)h * 64;
  __shared__ bf16 skf[8][64], sv[8][64];
  float accum[16];
#pragma unroll
  for (int i = 0; i < 16; ++i) accum[i] = 0.f;
  float ks = 0.f;
  const int tt = tid >> 5, cc = (tid & 31) << 1;
  for (int t0 = 0; t0 < 512; t0 += 8) {
    __syncthreads();
    const size_t base = (grow0 + t0 + tt) * 1024 + cbase + cc;
    *(uint32_t*)&skf[tt][cc] = *(const uint32_t*)(kf + base);
    *(uint32_t*)&sv[tt][cc]  = *(const uint32_t*)(v + base);
    __syncthreads();
#pragma unroll
    for (int q = 0; q < 8; ++q) {
      const float vv = (float)sv[q][e];
#pragma unroll
      for (int dd = 0; dd < 16; ++dd)
        accum[dd] += (float)skf[q][dg * 16 + dd] * vv;
    }
    if (tid < 64) {
#pragma unroll
      for (int q = 0; q < 8; ++q) ks += (float)skf[q][tid];
    }
  }
  float* op = kv_part + (size_t)blockIdx.x * 4096 + (size_t)(dg * 16) * 64 + e;
#pragma unroll
  for (int dd = 0; dd < 16; ++dd) op[dd * 64] = accum[dd];
  if (tid < 64) ksum_part[(size_t)blockIdx.x * 64 + tid] = ks;
}

__global__ __launch_bounds__(256) void kv_reduce(
    const float* __restrict__ kvp, const float* __restrict__ ksp,
    float* __restrict__ kvf, float* __restrict__ ksf)
{
  const int bh = blockIdx.x;
  const int tid = threadIdx.x;
  for (int i = tid; i < 4096; i += 256) {
    float s = 0.f;
#pragma unroll
    for (int ch = 0; ch < 8; ++ch) s += kvp[((size_t)bh * 8 + ch) * 4096 + i];
    kvf[(size_t)bh * 4096 + i] = s;
  }
  if (tid < 64) {
    float s = 0.f;
#pragma unroll
    for (int ch = 0; ch < 8; ++ch) s += ksp[((size_t)bh * 8 + ch) * 64 + tid];
    ksf[(size_t)bh * 64 + tid] = s;
  }
}

// ---------------------------------------------------------------------------
// attn out: out[t,e] = (qf[t,:].kv[:,e]) / (qf[t,:].ksum + 1e-6) -> bf16
// ---------------------------------------------------------------------------
__global__ __launch_bounds__(256) void attn_out_kernel(
    const bf16* __restrict__ qf, const float* __restrict__ kvf,
    const float* __restrict__ ksf, bf16* __restrict__ attn)
{
  const int bh = blockIdx.x >> 6, rb = blockIdx.x & 63;
  const int b = bh >> 4, h = bh & 15;
  const int tid = threadIdx.x;
  const int e = tid & 63, rbase = (tid >> 6) << 4;
  __shared__ __align__(16) bf16 sqf[64][64];
  __shared__ float sks[64];
  const size_t grow0 = (size_t)b * 4096 + (size_t)rb * 64;

  {
    const int rr = tid >> 2, c0 = (tid & 3) << 4;
    const bf16* src = qf + (grow0 + rr) * 1024 + h * 64 + c0;
    *(bf16x8*)&sqf[rr][c0]     = *(const bf16x8*)src;
    *(bf16x8*)&sqf[rr][c0 + 8] = *(const bf16x8*)(src + 8);
  }
  if (tid < 64) sks[tid] = ksf[(size_t)bh * 64 + tid];

  float kcol[64];
#pragma unroll
  for (int d = 0; d < 64; ++d) kcol[d] = kvf[(size_t)bh * 4096 + d * 64 + e];

  __syncthreads();

  for (int rr = 0; rr < 16; ++rr) {
    const int r = rbase + rr;
    bf16x8 q8[8];
#pragma unroll
    for (int i = 0; i < 8; ++i) q8[i] = *(const bf16x8*)&sqf[r][i * 8];
    float sk = 0.f, sv = 0.f;
#pragma unroll
    for (int i = 0; i < 8; ++i)
#pragma unroll
      for (int jj = 0; jj < 8; ++jj) {
        const float qd = (float)q8[i][jj];
        sk += qd * sks[i * 8 + jj];
        sv += qd * kcol[i * 8 + jj];
      }
    attn[(grow0 + r) * 1024 + h * 64 + e] = (bf16)(sv / (sk + 1e-6f));
  }
}

// ---------------------------------------------------------------------------
// launch
// ---------------------------------------------------------------------------
extern "C" void kernel_launch(void* const* d_in, const int* in_sizes, int n_in,
                              void* d_out, int out_size, void* d_ws, size_t ws_size,
                              hipStream_t stream)
{
  const float* x    = (const float*)d_in[0];
  const float* ln1w = (const float*)d_in[1];
  const float* ln1b = (const float*)d_in[2];
  const float* qw   = (const float*)d_in[3];
  const float* qb   = (const float*)d_in[4];
  const float* kw   = (const float*)d_in[5];
  const float* kb   = (const float*)d_in[6];
  const float* vw   = (const float*)d_in[7];
  const float* vb   = (const float*)d_in[8];
  const float* ow   = (const float*)d_in[9];
  const float* ob   = (const float*)d_in[10];
  const float* ln2w = (const float*)d_in[11];
  const float* ln2b = (const float*)d_in[12];
  const float* fcw  = (const float*)d_in[13];
  const float* fcb  = (const float*)d_in[14];
  const float* pjw  = (const float*)d_in[15];
  const float* pjb  = (const float*)d_in[16];
  float* out = (float*)d_out;
  char* ws = (char*)d_ws;

  constexpr size_t O_LNX  = 0;
  constexpr size_t O_QF   = 33554432;
  constexpr size_t O_KF   = 67108864;
  constexpr size_t O_V    = 100663296;
  constexpr size_t O_HMLP = 0;
  constexpr size_t O_KVP  = 134217728;
  constexpr size_t O_KSP  = 142606336;
  constexpr size_t O_KVF  = 142737408;
  constexpr size_t O_KSF  = 143785984;
  constexpr size_t O_ATTN = 143802368;
  constexpr size_t O_LN2  = 177356800;
  constexpr size_t O_WQ   = 210911232;
  constexpr size_t O_WK   = 213008384;
  constexpr size_t O_WV   = 215105536;
  constexpr size_t O_WO   = 217202688;
  constexpr size_t O_WFC  = 219299840;
  constexpr size_t O_WPJ  = 227688448;

  bf16* lnx  = (bf16*)(ws + O_LNX);
  bf16* qfb  = (bf16*)(ws + O_QF);
  bf16* kfb  = (bf16*)(ws + O_KF);
  bf16* vbuf = (bf16*)(ws + O_V);
  bf16* hmlp = (bf16*)(ws + O_HMLP);
  float* kvp = (float*)(ws + O_KVP);
  float* ksp = (float*)(ws + O_KSP);
  float* kvf = (float*)(ws + O_KVF);
  float* ksf = (float*)(ws + O_KSF);
  bf16* attn = (bf16*)(ws + O_ATTN);
  bf16* ln2h = (bf16*)(ws + O_LN2);
  bf16* wqT  = (bf16*)(ws + O_WQ);
  bf16* wkT  = (bf16*)(ws + O_WK);
  bf16* wvT  = (bf16*)(ws + O_WV);
  bf16* woT  = (bf16*)(ws + O_WO);
  bf16* wfcT = (bf16*)(ws + O_WFC);
  bf16* wpjT = (bf16*)(ws + O_WPJ);

  const dim3 tb(32, 8);
  transpose_cast<<<dim3(32, 32),  tb, 0, stream>>>(qw,  wqT, 1024, 1024);
  transpose_cast<<<dim3(32, 32),  tb, 0, stream>>>(kw,  wkT, 1024, 1024);
  transpose_cast<<<dim3(32, 32),  tb, 0, stream>>>(vw,  wvT, 1024, 1024);
  transpose_cast<<<dim3(32, 32),  tb, 0, stream>>>(ow,  woT, 1024, 1024);
  transpose_cast<<<dim3(128, 32), tb, 0, stream>>>(fcw, wfcT, 1024, 4096);
  transpose_cast<<<dim3(32, 128), tb, 0, stream>>>(pjw, wpjT, 4096, 1024);

  ln_row<<<16384, 256, 0, stream>>>(x, ln1w, ln1b, lnx);

  gemm256<1><<<256, 512, 0, stream>>>(lnx, wqT, qb, nullptr, qfb, 16384, 1024, 1024, 4);
  gemm256<1><<<256, 512, 0, stream>>>(lnx, wkT, kb, nullptr, kfb, 16384, 1024, 1024, 4);
  gemm256<0><<<256, 512, 0, stream>>>(lnx, wvT, vb, nullptr, vbuf, 16384, 1024, 1024, 4);

  kv_part_kernel<<<512, 256, 0, stream>>>(kfb, vbuf, kvp, ksp);
  kv_reduce<<<64, 256, 0, stream>>>(kvp, ksp, kvf, ksf);
  attn_out_kernel<<<4096, 256, 0, stream>>>(qfb, kvf, ksf, attn);

  // y1 = x + attn @ o_w + o_b   (f32 into d_out)
  gemm256<2><<<256, 512, 0, stream>>>(attn, woT, ob, x, out, 16384, 1024, 1024, 4);

  ln_row<<<16384, 256, 0, stream>>>(out, ln2w, ln2b, ln2h);

  gemm256<3><<<1024, 512, 0, stream>>>(ln2h, wfcT, fcb, nullptr, hmlp, 16384, 4096, 1024, 16);

  // out = y1 + h_mlp @ proj_w + proj_b  (in-place on d_out: read-before-write)
  gemm256<2><<<256, 512, 0, stream>>>(hmlp, wpjT, pjb, out, out, 16384, 1024, 4096, 4);
}

// Round 3
// 720.632 us; speedup vs baseline: 1.3151x; 1.0190x over previous
//
#include <hip/hip_runtime.h>
#include <hip/hip_bf16.h>
#include <cstdint>
#include <cstddef>

typedef __bf16 bf16;
typedef __bf16 bf16x8 __attribute__((ext_vector_type(8)));
typedef __bf16 bf16x4 __attribute__((ext_vector_type(4)));
typedef float  f32x4  __attribute__((ext_vector_type(4)));

typedef __attribute__((address_space(1))) void gvoid_t;
typedef __attribute__((address_space(3))) void lvoid_t;

// async global->LDS, 16B per lane; LDS dest must be wave-uniform base (HW adds lane*16)
#define GLD_LDS16(g, l) __builtin_amdgcn_global_load_lds( \
    (gvoid_t*)(uintptr_t)(g), (lvoid_t*)(uint32_t)(uintptr_t)(l), 16, 0, 0)

#define SBAR() __builtin_amdgcn_s_barrier()
#define WAIT_VM0() asm volatile("s_waitcnt vmcnt(0)" ::: "memory")

// ---------------------------------------------------------------------------
// Weight transpose + f32->bf16 cast:  in [R][C] f32  ->  out [C][R] bf16
// ---------------------------------------------------------------------------
__global__ __launch_bounds__(256) void transpose_cast(
    const float* __restrict__ in, bf16* __restrict__ out, int R, int C)
{
  __shared__ float tile[32][33];
  const int bx = blockIdx.x;   // C/32
  const int by = blockIdx.y;   // R/32
  const int tx = threadIdx.x;  // 0..31
  const int ty = threadIdx.y;  // 0..7
#pragma unroll
  for (int i = 0; i < 32; i += 8)
    tile[ty + i][tx] = in[(size_t)(by * 32 + ty + i) * C + bx * 32 + tx];
  __syncthreads();
#pragma unroll
  for (int i = 0; i < 32; i += 8)
    out[(size_t)(bx * 32 + ty + i) * R + by * 32 + tx] = (bf16)tile[tx][ty + i];
}

// ---------------------------------------------------------------------------
// LayerNorm over H=1024, f32 in -> bf16 out. One block (256 thr) per row.
// ---------------------------------------------------------------------------
__global__ __launch_bounds__(256) void ln_row(
    const float* __restrict__ x, const float* __restrict__ w,
    const float* __restrict__ b, bf16* __restrict__ out)
{
  const int row = blockIdx.x;
  const int tid = threadIdx.x;
  const float4 v = ((const float4*)(x + (size_t)row * 1024))[tid];
  float s  = v.x + v.y + v.z + v.w;
  float ss = v.x * v.x + v.y * v.y + v.z * v.z + v.w * v.w;
#pragma unroll
  for (int off = 32; off > 0; off >>= 1) {
    s  += __shfl_down(s, off);
    ss += __shfl_down(ss, off);
  }
  __shared__ float red[8];
  const int wid = tid >> 6, lane = tid & 63;
  if (lane == 0) { red[wid] = s; red[4 + wid] = ss; }
  __syncthreads();
  s  = red[0] + red[1] + red[2] + red[3];
  ss = red[4] + red[5] + red[6] + red[7];
  const float mu   = s * (1.f / 1024.f);
  const float var  = ss * (1.f / 1024.f) - mu * mu;
  const float rstd = rsqrtf(var + 1e-5f);
  const float4 wv = ((const float4*)w)[tid];
  const float4 bv = ((const float4*)b)[tid];
  bf16x4 ov;
  ov[0] = (bf16)((v.x - mu) * rstd * wv.x + bv.x);
  ov[1] = (bf16)((v.y - mu) * rstd * wv.y + bv.y);
  ov[2] = (bf16)((v.z - mu) * rstd * wv.z + bv.z);
  ov[3] = (bf16)((v.w - mu) * rstd * wv.w + bv.w);
  *(bf16x4*)(out + (size_t)row * 1024 + tid * 4) = ov;
}

// ---------------------------------------------------------------------------
// 256x256 GEMM, 1 barrier + 1 vmcnt per K-tile (BK=64), 64-MFMA clusters.
// C[M,N] = A[M,K] (bf16) * BT[N,K]^T (bf16) + bias.
// 512 threads = 8 waves (2M x 4N); per-wave 128x64 out (8x4 16x16x32 frags).
// LDS 128KB: dbuf x {A [256][64], B [256][64]} bf16, 8-slot XOR swizzle
// (slot ^= row&7, 16B slots) applied to BOTH gld_lds source and ds_read.
// Loads for tile kt+1 issue at start of tile kt -> vmcnt(0) at tile end ~free.
// EPI: 0 bias->bf16 | 1 bias->elu+1->bf16 | 2 bias+resid->f32 | 3 bias->gelu->bf16
// ---------------------------------------------------------------------------
template <int EPI>
__global__ __launch_bounds__(512, 2) void gemm256(
    const bf16* __restrict__ A, const bf16* __restrict__ BT,
    const float* __restrict__ bias, const float* __restrict__ resid,
    void* __restrict__ outp, int M, int N, int K, int nx)
{
  __shared__ __align__(16) char lds[131072];
  const int tid  = threadIdx.x;
  const int wid  = tid >> 6, lane = tid & 63;
  const int wr   = wid >> 2, wc = wid & 3;
  const int ln15 = lane & 15, lhi = lane >> 4;

  // chunked XCD swizzle + row-major logical tile order
  const int nwg = (int)gridDim.x;
  const int cpx = nwg >> 3;
  const int bid = (int)blockIdx.x;
  const int lg  = (bid & 7) * cpx + (bid >> 3);
  const int bx  = lg % nx, by = lg / nx;
  const int row0 = by << 8, col0 = bx << 8;

  // staging: 4 gld_lds per matrix per tile; issue i covers rows i*64+(tid>>3),
  // 16B slot (tid&7) in LDS holding global slot (tid&7)^(row&7).
  const int srow  = tid >> 3;                  // 0..63
  const int sslot = (tid & 7) ^ (srow & 7);
  const bf16* aS = A  + (size_t)(row0 + srow) * K + sslot * 8;
  const bf16* bS = BT + (size_t)(col0 + srow) * K + sslot * 8;
  const size_t rjump = (size_t)K << 6;         // +64 rows
  char* ldsW = lds + wid * 1024;               // per-wave linear dest base

  // swizzled read offsets (row&7 == ln15&7 for all frags: row steps are x16)
  const int rAb = (wr << 7) + ln15;
  const int rBb = (wc << 6) + ln15;
  const int sl0 = lhi ^ (ln15 & 7);
  const int sl1 = (4 + lhi) ^ (ln15 & 7);
  const int aOff0 = rAb * 128 + sl0 * 16;
  const int aOff1 = rAb * 128 + sl1 * 16;
  const int bOff0 = rBb * 128 + sl0 * 16 + 65536;
  const int bOff1 = rBb * 128 + sl1 * 16 + 65536;

  f32x4 acc[8][4] = {};
  const int nt = K >> 6;

#define STG(D, KT) do { \
    const bf16* ga_ = aS + (size_t)(KT) * 64; \
    const bf16* gb_ = bS + (size_t)(KT) * 64; \
    char* la_ = ldsW + (D) * 32768; \
    char* lb_ = la_ + 65536; \
    GLD_LDS16(ga_,             la_);         GLD_LDS16(gb_,             lb_); \
    GLD_LDS16(ga_ + rjump,     la_ + 8192);  GLD_LDS16(gb_ + rjump,     lb_ + 8192); \
    GLD_LDS16(ga_ + 2 * rjump, la_ + 16384); GLD_LDS16(gb_ + 2 * rjump, lb_ + 16384); \
    GLD_LDS16(ga_ + 3 * rjump, la_ + 24576); GLD_LDS16(gb_ + 3 * rjump, lb_ + 24576); \
  } while (0)

  STG(0, 0);
  WAIT_VM0();
  SBAR();

  for (int kt = 0; kt < nt; ++kt) {
    const int d = kt & 1;
    const char* base = (const char*)lds + d * 32768;
    if (kt + 1 < nt) STG(d ^ 1, kt + 1);

    bf16x8 a0[8], b0[4], a1[8], b1[4];
#pragma unroll
    for (int m = 0; m < 8; ++m) a0[m] = *(const bf16x8*)(base + aOff0 + m * 2048);
#pragma unroll
    for (int n = 0; n < 4; ++n) b0[n] = *(const bf16x8*)(base + bOff0 + n * 2048);
#pragma unroll
    for (int m = 0; m < 8; ++m) a1[m] = *(const bf16x8*)(base + aOff1 + m * 2048);
#pragma unroll
    for (int n = 0; n < 4; ++n) b1[n] = *(const bf16x8*)(base + bOff1 + n * 2048);

    __builtin_amdgcn_s_setprio(1);
#pragma unroll
    for (int m = 0; m < 8; ++m)
#pragma unroll
      for (int n = 0; n < 4; ++n)
        acc[m][n] = __builtin_amdgcn_mfma_f32_16x16x32_bf16(a0[m], b0[n], acc[m][n], 0, 0, 0);
#pragma unroll
    for (int m = 0; m < 8; ++m)
#pragma unroll
      for (int n = 0; n < 4; ++n)
        acc[m][n] = __builtin_amdgcn_mfma_f32_16x16x32_bf16(a1[m], b1[n], acc[m][n], 0, 0, 0);
    __builtin_amdgcn_s_setprio(0);

    WAIT_VM0();   // kt+1 loads issued a full tile ago -> near-free drain
    SBAR();
  }
#undef STG

  // epilogue
  const int lr4 = lhi << 2;
#pragma unroll
  for (int m = 0; m < 8; ++m) {
#pragma unroll
    for (int n = 0; n < 4; ++n) {
      const int c_i = col0 + wc * 64 + n * 16 + ln15;
      const float bv = bias[c_i];
#pragma unroll
      for (int j = 0; j < 4; ++j) {
        const int r_i = row0 + wr * 128 + m * 16 + lr4 + j;
        const size_t idx = (size_t)r_i * N + c_i;
        float val = acc[m][n][j] + bv;
        if constexpr (EPI == 0) {
          ((bf16*)outp)[idx] = (bf16)val;
        } else if constexpr (EPI == 1) {
          ((bf16*)outp)[idx] = (bf16)(val > 0.f ? val + 1.f : __expf(val));
        } else if constexpr (EPI == 2) {
          ((float*)outp)[idx] = val + resid[idx];
        } else {
          const float u  = 0.7978845608028654f * (val + 0.044715f * val * val * val);
          const float th = 1.f - 2.f / (__expf(2.f * u) + 1.f);
          ((bf16*)outp)[idx] = (bf16)(0.5f * val * (1.f + th));
        }
      }
    }
  }
}

// ---------------------------------------------------------------------------
// kv partials: per (b,h) and 512-token chunk, kv[d][e] = sum_t kf[t,d]*v[t,e],
// ksum[d] = sum_t kf[t,d].  grid = 64 heads * 8 chunks.
// ---------------------------------------------------------------------------
__global__ __launch_bounds__(256) void kv_part_kernel(
    const bf16* __restrict__ kf, const bf16* __restrict__ v,
    float* __restrict__ kv_part, float* __restrict__ ksum_part)
{
  const int bh = blockIdx.x >> 3, ch = blockIdx.x & 7;
  const int b = bh >> 4, h = bh & 15;
  const int tid = threadIdx.x;
  const int e = tid & 63, dg = tid >> 6;
  const size_t grow0 = (size_t)b * 4096 + (size_t)ch * 512;
  const size_t cbase = (size_t)h * 64;
  __shared__ bf16 skf[8][64], sv[8][64];
  float accum[16];
#pragma unroll
  for (int i = 0; i < 16; ++i) accum[i] = 0.f;
  float ks = 0.f;
  const int tt = tid >> 5, cc = (tid & 31) << 1;
  for (int t0 = 0; t0 < 512; t0 += 8) {
    __syncthreads();
    const size_t base = (grow0 + t0 + tt) * 1024 + cbase + cc;
    *(uint32_t*)&skf[tt][cc] = *(const uint32_t*)(kf + base);
    *(uint32_t*)&sv[tt][cc]  = *(const uint32_t*)(v + base);
    __syncthreads();
#pragma unroll
    for (int q = 0; q < 8; ++q) {
      const float vv = (float)sv[q][e];
#pragma unroll
      for (int dd = 0; dd < 16; ++dd)
        accum[dd] += (float)skf[q][dg * 16 + dd] * vv;
    }
    if (tid < 64) {
#pragma unroll
      for (int q = 0; q < 8; ++q) ks += (float)skf[q][tid];
    }
  }
  float* op = kv_part + (size_t)blockIdx.x * 4096 + (size_t)(dg * 16) * 64 + e;
#pragma unroll
  for (int dd = 0; dd < 16; ++dd) op[dd * 64] = accum[dd];
  if (tid < 64) ksum_part[(size_t)blockIdx.x * 64 + tid] = ks;
}

__global__ __launch_bounds__(256) void kv_reduce(
    const float* __restrict__ kvp, const float* __restrict__ ksp,
    float* __restrict__ kvf, float* __restrict__ ksf)
{
  const int bh = blockIdx.x;
  const int tid = threadIdx.x;
  for (int i = tid; i < 4096; i += 256) {
    float s = 0.f;
#pragma unroll
    for (int ch = 0; ch < 8; ++ch) s += kvp[((size_t)bh * 8 + ch) * 4096 + i];
    kvf[(size_t)bh * 4096 + i] = s;
  }
  if (tid < 64) {
    float s = 0.f;
#pragma unroll
    for (int ch = 0; ch < 8; ++ch) s += ksp[((size_t)bh * 8 + ch) * 64 + tid];
    ksf[(size_t)bh * 64 + tid] = s;
  }
}

// ---------------------------------------------------------------------------
// attn out: out[t,e] = (qf[t,:].kv[:,e]) / (qf[t,:].ksum + 1e-6) -> bf16
// ---------------------------------------------------------------------------
__global__ __launch_bounds__(256) void attn_out_kernel(
    const bf16* __restrict__ qf, const float* __restrict__ kvf,
    const float* __restrict__ ksf, bf16* __restrict__ attn)
{
  const int bh = blockIdx.x >> 6, rb = blockIdx.x & 63;
  const int b = bh >> 4, h = bh & 15;
  const int tid = threadIdx.x;
  const int e = tid & 63, rbase = (tid >> 6) << 4;
  __shared__ __align__(16) bf16 sqf[64][64];
  __shared__ float sks[64];
  const size_t grow0 = (size_t)b * 4096 + (size_t)rb * 64;

  {
    const int rr = tid >> 2, c0 = (tid & 3) << 4;
    const bf16* src = qf + (grow0 + rr) * 1024 + h * 64 + c0;
    *(bf16x8*)&sqf[rr][c0]     = *(const bf16x8*)src;
    *(bf16x8*)&sqf[rr][c0 + 8] = *(const bf16x8*)(src + 8);
  }
  if (tid < 64) sks[tid] = ksf[(size_t)bh * 64 + tid];

  float kcol[64];
#pragma unroll
  for (int d = 0; d < 64; ++d) kcol[d] = kvf[(size_t)bh * 4096 + d * 64 + e];

  __syncthreads();

  for (int rr = 0; rr < 16; ++rr) {
    const int r = rbase + rr;
    bf16x8 q8[8];
#pragma unroll
    for (int i = 0; i < 8; ++i) q8[i] = *(const bf16x8*)&sqf[r][i * 8];
    float sk = 0.f, sv = 0.f;
#pragma unroll
    for (int i = 0; i < 8; ++i)
#pragma unroll
      for (int jj = 0; jj < 8; ++jj) {
        const float qd = (float)q8[i][jj];
        sk += qd * sks[i * 8 + jj];
        sv += qd * kcol[i * 8 + jj];
      }
    attn[(grow0 + r) * 1024 + h * 64 + e] = (bf16)(sv / (sk + 1e-6f));
  }
}

// ---------------------------------------------------------------------------
// launch
// ---------------------------------------------------------------------------
extern "C" void kernel_launch(void* const* d_in, const int* in_sizes, int n_in,
                              void* d_out, int out_size, void* d_ws, size_t ws_size,
                              hipStream_t stream)
{
  const float* x    = (const float*)d_in[0];
  const float* ln1w = (const float*)d_in[1];
  const float* ln1b = (const float*)d_in[2];
  const float* qw   = (const float*)d_in[3];
  const float* qb   = (const float*)d_in[4];
  const float* kw   = (const float*)d_in[5];
  const float* kb   = (const float*)d_in[6];
  const float* vw   = (const float*)d_in[7];
  const float* vb   = (const float*)d_in[8];
  const float* ow   = (const float*)d_in[9];
  const float* ob   = (const float*)d_in[10];
  const float* ln2w = (const float*)d_in[11];
  const float* ln2b = (const float*)d_in[12];
  const float* fcw  = (const float*)d_in[13];
  const float* fcb  = (const float*)d_in[14];
  const float* pjw  = (const float*)d_in[15];
  const float* pjb  = (const float*)d_in[16];
  float* out = (float*)d_out;
  char* ws = (char*)d_ws;

  constexpr size_t O_LNX  = 0;
  constexpr size_t O_QF   = 33554432;
  constexpr size_t O_KF   = 67108864;
  constexpr size_t O_V    = 100663296;
  constexpr size_t O_HMLP = 0;
  constexpr size_t O_KVP  = 134217728;
  constexpr size_t O_KSP  = 142606336;
  constexpr size_t O_KVF  = 142737408;
  constexpr size_t O_KSF  = 143785984;
  constexpr size_t O_ATTN = 143802368;
  constexpr size_t O_LN2  = 177356800;
  constexpr size_t O_WQ   = 210911232;
  constexpr size_t O_WK   = 213008384;
  constexpr size_t O_WV   = 215105536;
  constexpr size_t O_WO   = 217202688;
  constexpr size_t O_WFC  = 219299840;
  constexpr size_t O_WPJ  = 227688448;

  bf16* lnx  = (bf16*)(ws + O_LNX);
  bf16* qfb  = (bf16*)(ws + O_QF);
  bf16* kfb  = (bf16*)(ws + O_KF);
  bf16* vbuf = (bf16*)(ws + O_V);
  bf16* hmlp = (bf16*)(ws + O_HMLP);
  float* kvp = (float*)(ws + O_KVP);
  float* ksp = (float*)(ws + O_KSP);
  float* kvf = (float*)(ws + O_KVF);
  float* ksf = (float*)(ws + O_KSF);
  bf16* attn = (bf16*)(ws + O_ATTN);
  bf16* ln2h = (bf16*)(ws + O_LN2);
  bf16* wqT  = (bf16*)(ws + O_WQ);
  bf16* wkT  = (bf16*)(ws + O_WK);
  bf16* wvT  = (bf16*)(ws + O_WV);
  bf16* woT  = (bf16*)(ws + O_WO);
  bf16* wfcT = (bf16*)(ws + O_WFC);
  bf16* wpjT = (bf16*)(ws + O_WPJ);

  const dim3 tb(32, 8);
  transpose_cast<<<dim3(32, 32),  tb, 0, stream>>>(qw,  wqT, 1024, 1024);
  transpose_cast<<<dim3(32, 32),  tb, 0, stream>>>(kw,  wkT, 1024, 1024);
  transpose_cast<<<dim3(32, 32),  tb, 0, stream>>>(vw,  wvT, 1024, 1024);
  transpose_cast<<<dim3(32, 32),  tb, 0, stream>>>(ow,  woT, 1024, 1024);
  transpose_cast<<<dim3(128, 32), tb, 0, stream>>>(fcw, wfcT, 1024, 4096);
  transpose_cast<<<dim3(32, 128), tb, 0, stream>>>(pjw, wpjT, 4096, 1024);

  ln_row<<<16384, 256, 0, stream>>>(x, ln1w, ln1b, lnx);

  gemm256<1><<<256, 512, 0, stream>>>(lnx, wqT, qb, nullptr, qfb, 16384, 1024, 1024, 4);
  gemm256<1><<<256, 512, 0, stream>>>(lnx, wkT, kb, nullptr, kfb, 16384, 1024, 1024, 4);
  gemm256<0><<<256, 512, 0, stream>>>(lnx, wvT, vb, nullptr, vbuf, 16384, 1024, 1024, 4);

  kv_part_kernel<<<512, 256, 0, stream>>>(kfb, vbuf, kvp, ksp);
  kv_reduce<<<64, 256, 0, stream>>>(kvp, ksp, kvf, ksf);
  attn_out_kernel<<<4096, 256, 0, stream>>>(qfb, kvf, ksf, attn);

  // y1 = x + attn @ o_w + o_b   (f32 into d_out)
  gemm256<2><<<256, 512, 0, stream>>>(attn, woT, ob, x, out, 16384, 1024, 1024, 4);

  ln_row<<<16384, 256, 0, stream>>>(out, ln2w, ln2b, ln2h);

  gemm256<3><<<1024, 512, 0, stream>>>(ln2h, wfcT, fcb, nullptr, hmlp, 16384, 4096, 1024, 16);

  // out = y1 + h_mlp @ proj_w + proj_b  (in-place on d_out: read-before-write)
  gemm256<2><<<256, 512, 0, stream>>>(hmlp, wpjT, pjb, out, out, 16384, 1024, 4096, 4);
}